// Round 11
// baseline (408.325 us; speedup 1.0000x reference)
//
#include <hip/hip_runtime.h>
#include <cstdint>
#include <cstddef>

#define BS   8
#define C    256
#define C2   128
#define NPIX 4096

typedef unsigned short u16;
typedef unsigned int   u32;
typedef __bf16 bf16_t;
typedef bf16_t bf16x8 __attribute__((ext_vector_type(8)));
typedef float  f32x16 __attribute__((ext_vector_type(16)));

__device__ __forceinline__ u16 f2bf(float f) {
    union { float ff; u32 i; } x; x.ff = f;
    u32 r = x.i + 0x7fffu + ((x.i >> 16) & 1u);  // RNE
    return (u16)(r >> 16);
}
__device__ __forceinline__ float bf2f(u16 h) {
    union { u32 i; float f; } x; x.i = (u32)h << 16; return x.f;
}
__device__ __forceinline__ u32 pk2(u16 a, u16 b) { return (u32)a | ((u32)b << 16); }

// ---------------- W pre-split: fragment-major hi/lo ------------------------
// W[o][c] fp32 -> Wh/Wl[c8*O + o][8] bf16.  W = Wh + Wl exact to ~2^-17.
__global__ __launch_bounds__(256)
void prep_w(const float* __restrict__ Wq, const float* __restrict__ Wk,
            const float* __restrict__ Wv,
            u16* __restrict__ qh, u16* __restrict__ ql,
            u16* __restrict__ kh, u16* __restrict__ kl,
            u16* __restrict__ vh, u16* __restrict__ vl) {
    const int z = blockIdx.y;                       // 0=q 1=k 2=v
    const int O = (z == 2) ? C : C2;                // O == CIN
    const int npair = O * O / 8;
    const int idx = blockIdx.x * 256 + threadIdx.x;
    if (idx >= npair) return;
    const int o  = idx & (O - 1);
    const int c8 = idx >> ((z == 2) ? 8 : 7);
    const float* src = (z == 0) ? Wq : (z == 1) ? Wk : Wv;
    u16* oh = (z == 0) ? qh : (z == 1) ? kh : vh;
    u16* ol = (z == 0) ? ql : (z == 1) ? kl : vl;
    u16 h[8], l[8];
    #pragma unroll
    for (int j = 0; j < 8; ++j) {
        const float f = src[(size_t)o * O + c8 * 8 + j];
        h[j] = f2bf(f);
        l[j] = f2bf(f - bf2f(h[j]));
    }
    *(uint4*)(oh + (size_t)idx * 8) =
        make_uint4(pk2(h[0], h[1]), pk2(h[2], h[3]), pk2(h[4], h[5]), pk2(h[6], h[7]));
    *(uint4*)(ol + (size_t)idx * 8) =
        make_uint4(pk2(l[0], l[1]), pk2(l[2], l[3]), pk2(l[4], l[5]), pk2(l[6], l[7]));
}

// ---------------- fused projections: z=0 Q, z=1 K, z=2/3 V n-halves --------
__global__ __launch_bounds__(256, 4)
void proj_all(const u16* __restrict__ wqh, const u16* __restrict__ wql,
              const u16* __restrict__ wkh, const u16* __restrict__ wkl,
              const u16* __restrict__ wvh, const u16* __restrict__ wvl,
              const float* __restrict__ bq, const float* __restrict__ bk,
              const float* __restrict__ bv,
              const float* __restrict__ a2, const float* __restrict__ a1,
              const float* __restrict__ motion,
              u16* __restrict__ qout, u16* __restrict__ kout,
              u16* __restrict__ vout) {
    __shared__ __align__(16) u16 Xb[16][64][8];   // 16 KB (V path: [32][32][8])
    const int t  = threadIdx.x;
    const int w  = t >> 6;
    const int li = t & 31;
    const int hs = (t >> 5) & 1;
    const int z  = blockIdx.z;
    const int b  = blockIdx.y;

    if (z < 2) {
        // ---------------- Q / K : out [b][n][128] --------------------------
        const u16* wh = z ? wkh : wqh;
        const u16* wl = z ? wkl : wql;
        const float* bias = z ? bk : bq;
        const float* x    = z ? a1 : a2;
        u16* out          = z ? kout : qout;
        const int n0 = blockIdx.x * 64;
        {
            const int sn = t & 63;
            const float* xb = x + (size_t)b * C2 * NPIX + n0 + sn;
            #pragma unroll
            for (int q = 0; q < 4; ++q) {
                const int c8 = q * 4 + w;
                union { bf16_t e[8]; uint4 u4; } cv;
                #pragma unroll
                for (int j = 0; j < 8; ++j)
                    cv.e[j] = (bf16_t)xb[(size_t)(c8 * 8 + j) * NPIX];
                *(uint4*)&Xb[c8][sn][0] = cv.u4;
            }
        }
        __syncthreads();

        f32x16 acc[2];
        #pragma unroll
        for (int nt = 0; nt < 2; ++nt)
            #pragma unroll
            for (int e = 0; e < 16; ++e) acc[nt][e] = 0.f;

        const int ob = w * 32 + li;   // output channel (D col)
        #pragma unroll
        for (int ks = 0; ks < 8; ++ks) {
            const int c8 = ks * 2 + hs;
            const bf16x8 bh = *(const bf16x8*)(wh + ((size_t)c8 * C2 + ob) * 8);
            const bf16x8 bl = *(const bf16x8*)(wl + ((size_t)c8 * C2 + ob) * 8);
            #pragma unroll
            for (int nt = 0; nt < 2; ++nt) {
                const bf16x8 a = *(const bf16x8*)&Xb[c8][nt * 32 + li][0];
                acc[nt] = __builtin_amdgcn_mfma_f32_32x32x16_bf16(a, bh, acc[nt], 0, 0, 0);
                acc[nt] = __builtin_amdgcn_mfma_f32_32x32x16_bf16(a, bl, acc[nt], 0, 0, 0);
            }
        }

        const float bb = bias[ob];
        #pragma unroll
        for (int nt = 0; nt < 2; ++nt)
            #pragma unroll
            for (int r = 0; r < 16; ++r) {
                const int n = n0 + nt * 32 + (r & 3) + 8 * (r >> 2) + 4 * hs;
                out[((size_t)b * NPIX + n) * C2 + ob] = f2bf(acc[nt][r] + bb);
            }
    } else {
        // ---------------- V : out [b][o][n], n-tile 32 ---------------------
        u16 (*Xv)[32][8] = (u16 (*)[32][8])(&Xb[0][0][0]);
        const int n0 = blockIdx.x * 64 + (z - 2) * 32;
        {
            const int sn = t & 31;
            const int cg = t >> 5;
            const float* xb = motion + (size_t)b * C * NPIX + n0 + sn;
            #pragma unroll
            for (int r = 0; r < 4; ++r) {
                const int c8 = r * 8 + cg;
                union { bf16_t e[8]; uint4 u4; } cv;
                #pragma unroll
                for (int j = 0; j < 8; ++j)
                    cv.e[j] = (bf16_t)xb[(size_t)(c8 * 8 + j) * NPIX];
                *(uint4*)&Xv[c8][sn][0] = cv.u4;
            }
        }
        __syncthreads();

        f32x16 acc[2];
        #pragma unroll
        for (int ot = 0; ot < 2; ++ot)
            #pragma unroll
            for (int e = 0; e < 16; ++e) acc[ot][e] = 0.f;

        #pragma unroll
        for (int ks = 0; ks < 16; ++ks) {
            const int c8 = ks * 2 + hs;
            const bf16x8 xf = *(const bf16x8*)&Xv[c8][li][0];
            #pragma unroll
            for (int ot = 0; ot < 2; ++ot) {
                const int o = w * 64 + ot * 32 + li;
                const bf16x8 ah = *(const bf16x8*)(wvh + ((size_t)c8 * C + o) * 8);
                const bf16x8 al = *(const bf16x8*)(wvl + ((size_t)c8 * C + o) * 8);
                acc[ot] = __builtin_amdgcn_mfma_f32_32x32x16_bf16(ah, xf, acc[ot], 0, 0, 0);
                acc[ot] = __builtin_amdgcn_mfma_f32_32x32x16_bf16(al, xf, acc[ot], 0, 0, 0);
            }
        }

        #pragma unroll
        for (int ot = 0; ot < 2; ++ot)
            #pragma unroll
            for (int g = 0; g < 4; ++g) {
                const int orow = w * 64 + ot * 32 + 8 * g + 4 * hs;
                const float4 b4 = *(const float4*)&bv[orow];
                const size_t base = ((size_t)b * C + orow) * NPIX + n0 + li;
                vout[base]            = f2bf(acc[ot][g * 4 + 0] + b4.x);
                vout[base + NPIX]     = f2bf(acc[ot][g * 4 + 1] + b4.y);
                vout[base + 2 * NPIX] = f2bf(acc[ot][g * 4 + 2] + b4.z);
                vout[base + 3 * NPIX] = f2bf(acc[ot][g * 4 + 3] + b4.w);
            }
    }
}

// ----------------------------- MFMA attention v7 ---------------------------
// R10 body; only change: V LDS swizzle moved to 16B granularity.
//   store: 16B chunk m = (c&1)*4 + jblk at pos = m ^ (rc&7), row rc = c>>1
//   -> V writes 8 b64 -> 4 b128; V reads 32 b64 -> 16 b128 (same bytes,
//      uniform 8 touches/bank = b128 data minimum; addressing collapses to
//      2 per-lane bases + ct*1024 immediates since rc&7 is ct-invariant).
// Per-wave LDS ops per iter: 50 -> 30. Arithmetic bit-identical.
struct SR { uint4 k[2]; uint4 v[4]; };

__device__ __forceinline__ void stg_load(const u16* __restrict__ kg,
                                         const u16* __restrict__ vg,
                                         int jt, int t, SR& R) {
    const u16* kp = kg + (size_t)jt * 32 * 128;
    #pragma unroll
    for (int q = 0; q < 2; ++q)
        R.k[q] = *(const uint4*)(kp + (size_t)(t + 256 * q) * 8);
    const u16* vp = vg + jt * 32 + (t & 3) * 8;
    #pragma unroll
    for (int q = 0; q < 4; ++q)
        R.v[q] = *(const uint4*)(vp + (size_t)((t >> 2) + 64 * q) * NPIX);
}

__device__ __forceinline__ void stg_write(u16* __restrict__ kb, u16* __restrict__ vb,
                                          int t, const SR& R) {
    #pragma unroll
    for (int q = 0; q < 2; ++q) {
        const int idx = t + 256 * q;
        const int row = idx >> 4;
        const int ch  = (idx & 15) ^ (row & 15);
        *(uint4*)(kb + row * 128 + ch * 8) = R.k[q];
    }
    // V: chunk m = (c&1)*4 + (t&3), pos = m ^ (rc&7); m,pos are q-invariant
    {
        const int m   = ((t >> 2) & 1) * 4 + (t & 3);
        const int pos = m ^ ((t >> 3) & 7);
        u16* vwp = vb + (size_t)(t >> 3) * 64 + pos * 8;
        #pragma unroll
        for (int q = 0; q < 4; ++q)
            *(uint4*)(vwp + q * 2048) = R.v[q];   // rc = (t>>3) + 32q
    }
}

__global__ __launch_bounds__(256, 2)
void attn_mfma3(const u16* __restrict__ qt,   // [BS][NPIX][C2]
                const u16* __restrict__ kt,   // [BS][NPIX][C2]
                const u16* __restrict__ vn,   // [BS][C][NPIX]
                u16* __restrict__ opart0,     // bf16 partial O, j-half 0 (ws)
                u16* __restrict__ opart1,     // bf16 partial O, j-half 1 (ws)
                float* __restrict__ sbuf) {   // [2][BS][NPIX] partial sums
    __shared__ u16 Kb[2][32 * 128];
    __shared__ u16 Vb[2][128 * 64];

    const int t  = threadIdx.x;
    const int w  = t >> 6;
    const int li = t & 31;
    const int hs = (t >> 5) & 1;

    const int b  = blockIdx.x & 7;                 // batch <-> XCD affinity
    const int it = (blockIdx.x >> 3) & 31;
    const int h  = blockIdx.x >> 8;                // j-half
    const int i0 = it * 128;
    const int iw = i0 + w * 32 + li;
    const int j0 = h * 2048;

    bf16x8 qf[8];
    {
        const u16* qp = qt + ((size_t)b * NPIX + iw) * C2 + hs * 8;
        #pragma unroll
        for (int ct = 0; ct < 8; ++ct) qf[ct] = *(const bf16x8*)(qp + ct * 16);
    }

    f32x16 oacc[8];
    #pragma unroll
    for (int ct = 0; ct < 8; ++ct)
        #pragma unroll
        for (int e = 0; e < 16; ++e) oacc[ct][e] = 0.f;

    const u16* ktb = kt + ((size_t)b * NPIX + j0) * C2;
    const u16* vnb = vn + (size_t)b * C * NPIX + j0;

    SR R;
    stg_load(ktb, vnb, 0, t, R);
    stg_write(&Kb[0][0], &Vb[0][0], t, R);
    stg_load(ktb, vnb, 1, t, R);
    __syncthreads();

    float ssl = 0.f;
    for (int itr = 0; itr < 64; ++itr) {
        const int cur = itr & 1;
        if (itr < 63) {
            stg_write(&Kb[cur ^ 1][0], &Vb[cur ^ 1][0], t, R);
            if (itr < 62) stg_load(ktb, vnb, itr + 2, t, R);
        }
        const u16* kb = &Kb[cur][0];
        const u16* vb = &Vb[cur][0];

        // ---- S' = K Q^T  [32j x 32i]
        f32x16 s;
        #pragma unroll
        for (int e = 0; e < 16; ++e) s[e] = 0.f;
        {
            const int xr = li & 15;
            __builtin_amdgcn_s_setprio(1);
            #pragma unroll
            for (int ct = 0; ct < 8; ++ct) {
                const int ch = (ct * 2 + hs) ^ xr;
                const bf16x8 kf = *(const bf16x8*)(kb + li * 128 + ch * 8);
                s = __builtin_amdgcn_mfma_f32_32x32x16_bf16(kf, qf[ct], s, 0, 0, 0);
            }
            __builtin_amdgcn_s_setprio(0);
        }

        // ---- P = exp(S'), partial sums, pack bf16 pairs (native cvt)
        u32 pk[8];
        #pragma unroll
        for (int n = 0; n < 8; ++n) {
            const float p0 = __expf(s[2 * n]);
            const float p1 = __expf(s[2 * n + 1]);
            ssl += p0 + p1;
            union { bf16_t e[2]; u32 u; } cv;
            cv.e[0] = (bf16_t)p0;
            cv.e[1] = (bf16_t)p1;
            pk[n] = cv.u;
        }

        // ---- P' -> PV B-fragments via half-swap shuffle
        bf16x8 pf[2];
        #pragma unroll
        for (int seg = 0; seg < 2; ++seg) {
            const u32 A0 = pk[4 * seg + 0], A1 = pk[4 * seg + 1];
            const u32 A2 = pk[4 * seg + 2], A3 = pk[4 * seg + 3];
            const u32 own0 = hs ? A2 : A0, own1 = hs ? A3 : A1;
            const u32 snd0 = hs ? A0 : A2, snd1 = hs ? A1 : A3;
            const u32 rcv0 = (u32)__shfl_xor((int)snd0, 32, 64);
            const u32 rcv1 = (u32)__shfl_xor((int)snd1, 32, 64);
            union { u32 u[4]; bf16x8 v; } bb;
            bb.u[0] = hs ? rcv0 : own0;
            bb.u[1] = hs ? rcv1 : own1;
            bb.u[2] = hs ? own0 : rcv0;
            bb.u[3] = hs ? own1 : rcv1;
            pf[seg] = bb.v;
        }

        // ---- O += V P'  (b128 V reads: 2 bases, ct*1024 immediates)
        {
            const int mlo  = (li & 1) * 4 + hs;        // m for seg 0
            const int sx   = (li >> 1) & 7;
            const u16* vr0 = vb + (size_t)(li >> 1) * 64 + ((mlo    ) ^ sx) * 8;
            const u16* vr1 = vb + (size_t)(li >> 1) * 64 + ((mlo + 2) ^ sx) * 8;
            __builtin_amdgcn_s_setprio(1);
            #pragma unroll
            for (int ct = 0; ct < 8; ++ct) {
                union { uint4 g; bf16x8 v8; } u0, u1;
                u0.g = *(const uint4*)(vr0 + ct * 1024);
                oacc[ct] = __builtin_amdgcn_mfma_f32_32x32x16_bf16(u0.v8, pf[0], oacc[ct], 0, 0, 0);
                u1.g = *(const uint4*)(vr1 + ct * 1024);
                oacc[ct] = __builtin_amdgcn_mfma_f32_32x32x16_bf16(u1.v8, pf[1], oacc[ct], 0, 0, 0);
            }
            __builtin_amdgcn_s_setprio(0);
        }
        __syncthreads();
    }

    // ---- partial denominators
    ssl += __shfl_xor(ssl, 32, 64);
    if (hs == 0) sbuf[((size_t)h * BS + b) * NPIX + iw] = ssl;

    // ---- store unnormalized partial O (bf16, native cvt)
    u16* op = h ? opart1 : opart0;
    #pragma unroll
    for (int ct = 0; ct < 8; ++ct) {
        #pragma unroll
        for (int r = 0; r < 16; ++r) {
            const int c = ct * 32 + (r & 3) + 8 * (r >> 2) + 4 * hs;
            union { bf16_t e; u16 u; } cv;
            cv.e = (bf16_t)oacc[ct][r];
            op[((size_t)b * C + c) * NPIX + iw] = cv.u;
        }
    }
}

// ---- merge: out = (O1+O2)/(s1+s2); fuse = out*motion (bf16 partials) -------
__global__ __launch_bounds__(256)
void attn_merge(float* __restrict__ fuse, float* __restrict__ outp,
                const u16* __restrict__ pa, const u16* __restrict__ pb,
                const float* __restrict__ motion,
                const float* __restrict__ sbuf) {
    const size_t idx = ((size_t)blockIdx.x * 256 + threadIdx.x) * 8;
    const int n = (int)(idx & (NPIX - 1));
    const int b = (int)(idx >> 20);
    const uint4 A = *(const uint4*)(pa + idx);
    const uint4 B = *(const uint4*)(pb + idx);
    const u32 au[4] = {A.x, A.y, A.z, A.w};
    const u32 bu[4] = {B.x, B.y, B.z, B.w};
    float den[8];
    {
        const float* s0 = sbuf + (size_t)b * NPIX + n;
        const float* s1 = sbuf + (size_t)(BS + b) * NPIX + n;
        const float4 s0a = *(const float4*)s0;
        const float4 s0b = *(const float4*)(s0 + 4);
        const float4 s1a = *(const float4*)s1;
        const float4 s1b = *(const float4*)(s1 + 4);
        den[0] = s0a.x + s1a.x; den[1] = s0a.y + s1a.y;
        den[2] = s0a.z + s1a.z; den[3] = s0a.w + s1a.w;
        den[4] = s0b.x + s1b.x; den[5] = s0b.y + s1b.y;
        den[6] = s0b.z + s1b.z; den[7] = s0b.w + s1b.w;
    }
    float o[8];
    #pragma unroll
    for (int q = 0; q < 4; ++q) {
        o[2 * q]     = (bf2f((u16)(au[q] & 0xffffu)) + bf2f((u16)(bu[q] & 0xffffu))) / den[2 * q];
        o[2 * q + 1] = (bf2f((u16)(au[q] >> 16))     + bf2f((u16)(bu[q] >> 16)))     / den[2 * q + 1];
    }
    const float4 m0 = *(const float4*)(motion + idx);
    const float4 m1 = *(const float4*)(motion + idx + 4);
    *(float4*)(outp + idx)     = make_float4(o[0], o[1], o[2], o[3]);
    *(float4*)(outp + idx + 4) = make_float4(o[4], o[5], o[6], o[7]);
    *(float4*)(fuse + idx)     = make_float4(o[0] * m0.x, o[1] * m0.y, o[2] * m0.z, o[3] * m0.w);
    *(float4*)(fuse + idx + 4) = make_float4(o[4] * m1.x, o[5] * m1.y, o[6] * m1.z, o[7] * m1.w);
}

extern "C" void kernel_launch(void* const* d_in, const int* in_sizes, int n_in,
                              void* d_out, int out_size, void* d_ws, size_t ws_size,
                              hipStream_t stream) {
    const float* a1     = (const float*)d_in[0];  // appearance_1 -> k
    const float* a2     = (const float*)d_in[1];  // appearance_2 -> q
    const float* motion = (const float*)d_in[2];  // -> v, and fuse multiplier
    const float* Wq = (const float*)d_in[3];
    const float* bq = (const float*)d_in[4];
    const float* Wk = (const float*)d_in[5];
    const float* bk = (const float*)d_in[6];
    const float* Wv = (const float*)d_in[7];
    const float* bv = (const float*)d_in[8];

    float* outp = (float*)d_out;  // [fuse_out | out]
    float* slot0 = outp;                              // fuse_out
    float* slot1 = outp + (size_t)BS * C * NPIX;      // out

    // workspace: QT (8MB) | KT (8MB) | V (16MB) | sbuf (256KB) | W frags |
    //            bf16 partials pw0/pw1 (16.8MB each). Total ~67.4MB
    u16* qws = (u16*)d_ws;
    u16* kws = qws + (size_t)BS * C2 * NPIX;
    u16* vws = kws + (size_t)BS * C2 * NPIX;
    float* sbuf = (float*)(vws + (size_t)BS * C * NPIX);
    u16* wqh = (u16*)(sbuf + (size_t)2 * BS * NPIX);
    u16* wql = wqh + C2 * C2;
    u16* wkh = wql + C2 * C2;
    u16* wkl = wkh + C2 * C2;
    u16* wvh = wkl + C2 * C2;
    u16* wvl = wvh + C * C;
    u16* pw0 = wvl + C * C;
    u16* pw1 = pw0 + (size_t)BS * C * NPIX;

    const dim3 blk(256);
    prep_w<<<dim3(32, 3), blk, 0, stream>>>(Wq, Wk, Wv, wqh, wql, wkh, wkl, wvh, wvl);
    proj_all<<<dim3(NPIX / 64, BS, 4), blk, 0, stream>>>(
        wqh, wql, wkh, wkl, wvh, wvl, bq, bk, bv, a2, a1, motion, qws, kws, vws);

    attn_mfma3<<<dim3(512), blk, 0, stream>>>(qws, kws, vws, pw0, pw1, sbuf);

    attn_merge<<<dim3((BS * C * NPIX) / 2048), blk, 0, stream>>>(
        slot0, slot1, pw0, pw1, motion, sbuf);
}

// Round 12
// 295.729 us; speedup vs baseline: 1.3807x; 1.3807x over previous
//
#include <hip/hip_runtime.h>
#include <cstdint>
#include <cstddef>

#define BS   8
#define C    256
#define C2   128
#define NPIX 4096

typedef unsigned short u16;
typedef unsigned int   u32;
typedef __bf16 bf16_t;
typedef bf16_t bf16x8 __attribute__((ext_vector_type(8)));
typedef float  f32x16 __attribute__((ext_vector_type(16)));

__device__ __forceinline__ u16 f2bf(float f) {
    union { float ff; u32 i; } x; x.ff = f;
    u32 r = x.i + 0x7fffu + ((x.i >> 16) & 1u);  // RNE
    return (u16)(r >> 16);
}
__device__ __forceinline__ float bf2f(u16 h) {
    union { u32 i; float f; } x; x.i = (u32)h << 16; return x.f;
}
__device__ __forceinline__ u32 pk2(u16 a, u16 b) { return (u32)a | ((u32)b << 16); }

// ---------------- W pre-split: fragment-major hi/lo ------------------------
// W[o][c] fp32 -> Wh/Wl[c8*O + o][8] bf16.  W = Wh + Wl exact to ~2^-17.
__global__ __launch_bounds__(256)
void prep_w(const float* __restrict__ Wq, const float* __restrict__ Wk,
            const float* __restrict__ Wv,
            u16* __restrict__ qh, u16* __restrict__ ql,
            u16* __restrict__ kh, u16* __restrict__ kl,
            u16* __restrict__ vh, u16* __restrict__ vl) {
    const int z = blockIdx.y;                       // 0=q 1=k 2=v
    const int O = (z == 2) ? C : C2;                // O == CIN
    const int npair = O * O / 8;
    const int idx = blockIdx.x * 256 + threadIdx.x;
    if (idx >= npair) return;
    const int o  = idx & (O - 1);
    const int c8 = idx >> ((z == 2) ? 8 : 7);
    const float* src = (z == 0) ? Wq : (z == 1) ? Wk : Wv;
    u16* oh = (z == 0) ? qh : (z == 1) ? kh : vh;
    u16* ol = (z == 0) ? ql : (z == 1) ? kl : vl;
    u16 h[8], l[8];
    #pragma unroll
    for (int j = 0; j < 8; ++j) {
        const float f = src[(size_t)o * O + c8 * 8 + j];
        h[j] = f2bf(f);
        l[j] = f2bf(f - bf2f(h[j]));
    }
    *(uint4*)(oh + (size_t)idx * 8) =
        make_uint4(pk2(h[0], h[1]), pk2(h[2], h[3]), pk2(h[4], h[5]), pk2(h[6], h[7]));
    *(uint4*)(ol + (size_t)idx * 8) =
        make_uint4(pk2(l[0], l[1]), pk2(l[2], l[3]), pk2(l[4], l[5]), pk2(l[6], l[7]));
}

// ---------------- fused projections: z=0 Q, z=1 K, z=2/3 V n-halves --------
__global__ __launch_bounds__(256, 4)
void proj_all(const u16* __restrict__ wqh, const u16* __restrict__ wql,
              const u16* __restrict__ wkh, const u16* __restrict__ wkl,
              const u16* __restrict__ wvh, const u16* __restrict__ wvl,
              const float* __restrict__ bq, const float* __restrict__ bk,
              const float* __restrict__ bv,
              const float* __restrict__ a2, const float* __restrict__ a1,
              const float* __restrict__ motion,
              u16* __restrict__ qout, u16* __restrict__ kout,
              u16* __restrict__ vout) {
    __shared__ __align__(16) u16 Xb[16][64][8];   // 16 KB (V path: [32][32][8])
    const int t  = threadIdx.x;
    const int w  = t >> 6;
    const int li = t & 31;
    const int hs = (t >> 5) & 1;
    const int z  = blockIdx.z;
    const int b  = blockIdx.y;

    if (z < 2) {
        // ---------------- Q / K : out [b][n][128] --------------------------
        const u16* wh = z ? wkh : wqh;
        const u16* wl = z ? wkl : wql;
        const float* bias = z ? bk : bq;
        const float* x    = z ? a1 : a2;
        u16* out          = z ? kout : qout;
        const int n0 = blockIdx.x * 64;
        {
            const int sn = t & 63;
            const float* xb = x + (size_t)b * C2 * NPIX + n0 + sn;
            #pragma unroll
            for (int q = 0; q < 4; ++q) {
                const int c8 = q * 4 + w;
                union { bf16_t e[8]; uint4 u4; } cv;
                #pragma unroll
                for (int j = 0; j < 8; ++j)
                    cv.e[j] = (bf16_t)xb[(size_t)(c8 * 8 + j) * NPIX];
                *(uint4*)&Xb[c8][sn][0] = cv.u4;
            }
        }
        __syncthreads();

        f32x16 acc[2];
        #pragma unroll
        for (int nt = 0; nt < 2; ++nt)
            #pragma unroll
            for (int e = 0; e < 16; ++e) acc[nt][e] = 0.f;

        const int ob = w * 32 + li;   // output channel (D col)
        #pragma unroll
        for (int ks = 0; ks < 8; ++ks) {
            const int c8 = ks * 2 + hs;
            const bf16x8 bh = *(const bf16x8*)(wh + ((size_t)c8 * C2 + ob) * 8);
            const bf16x8 bl = *(const bf16x8*)(wl + ((size_t)c8 * C2 + ob) * 8);
            #pragma unroll
            for (int nt = 0; nt < 2; ++nt) {
                const bf16x8 a = *(const bf16x8*)&Xb[c8][nt * 32 + li][0];
                acc[nt] = __builtin_amdgcn_mfma_f32_32x32x16_bf16(a, bh, acc[nt], 0, 0, 0);
                acc[nt] = __builtin_amdgcn_mfma_f32_32x32x16_bf16(a, bl, acc[nt], 0, 0, 0);
            }
        }

        const float bb = bias[ob];
        #pragma unroll
        for (int nt = 0; nt < 2; ++nt)
            #pragma unroll
            for (int r = 0; r < 16; ++r) {
                const int n = n0 + nt * 32 + (r & 3) + 8 * (r >> 2) + 4 * hs;
                out[((size_t)b * NPIX + n) * C2 + ob] = f2bf(acc[nt][r] + bb);
            }
    } else {
        // ---------------- V : out [b][o][n], n-tile 32 ---------------------
        u16 (*Xv)[32][8] = (u16 (*)[32][8])(&Xb[0][0][0]);
        const int n0 = blockIdx.x * 64 + (z - 2) * 32;
        {
            const int sn = t & 31;
            const int cg = t >> 5;
            const float* xb = motion + (size_t)b * C * NPIX + n0 + sn;
            #pragma unroll
            for (int r = 0; r < 4; ++r) {
                const int c8 = r * 8 + cg;
                union { bf16_t e[8]; uint4 u4; } cv;
                #pragma unroll
                for (int j = 0; j < 8; ++j)
                    cv.e[j] = (bf16_t)xb[(size_t)(c8 * 8 + j) * NPIX];
                *(uint4*)&Xv[c8][sn][0] = cv.u4;
            }
        }
        __syncthreads();

        f32x16 acc[2];
        #pragma unroll
        for (int ot = 0; ot < 2; ++ot)
            #pragma unroll
            for (int e = 0; e < 16; ++e) acc[ot][e] = 0.f;

        #pragma unroll
        for (int ks = 0; ks < 16; ++ks) {
            const int c8 = ks * 2 + hs;
            const bf16x8 xf = *(const bf16x8*)&Xv[c8][li][0];
            #pragma unroll
            for (int ot = 0; ot < 2; ++ot) {
                const int o = w * 64 + ot * 32 + li;
                const bf16x8 ah = *(const bf16x8*)(wvh + ((size_t)c8 * C + o) * 8);
                const bf16x8 al = *(const bf16x8*)(wvl + ((size_t)c8 * C + o) * 8);
                acc[ot] = __builtin_amdgcn_mfma_f32_32x32x16_bf16(ah, xf, acc[ot], 0, 0, 0);
                acc[ot] = __builtin_amdgcn_mfma_f32_32x32x16_bf16(al, xf, acc[ot], 0, 0, 0);
            }
        }

        #pragma unroll
        for (int ot = 0; ot < 2; ++ot)
            #pragma unroll
            for (int g = 0; g < 4; ++g) {
                const int orow = w * 64 + ot * 32 + 8 * g + 4 * hs;
                const float4 b4 = *(const float4*)&bv[orow];
                const size_t base = ((size_t)b * C + orow) * NPIX + n0 + li;
                vout[base]            = f2bf(acc[ot][g * 4 + 0] + b4.x);
                vout[base + NPIX]     = f2bf(acc[ot][g * 4 + 1] + b4.y);
                vout[base + 2 * NPIX] = f2bf(acc[ot][g * 4 + 2] + b4.z);
                vout[base + 3 * NPIX] = f2bf(acc[ot][g * 4 + 3] + b4.w);
            }
    }
}

// ----------------------------- MFMA attention v3 ---------------------------
// Exact R10-benched body (145.0 us, session best). bf16 partial O to ws.
struct SR { uint4 k[2]; uint4 v[4]; };

__device__ __forceinline__ void stg_load(const u16* __restrict__ kg,
                                         const u16* __restrict__ vg,
                                         int jt, int t, SR& R) {
    const u16* kp = kg + (size_t)jt * 32 * 128;
    #pragma unroll
    for (int q = 0; q < 2; ++q)
        R.k[q] = *(const uint4*)(kp + (size_t)(t + 256 * q) * 8);
    const u16* vp = vg + jt * 32 + (t & 3) * 8;
    #pragma unroll
    for (int q = 0; q < 4; ++q)
        R.v[q] = *(const uint4*)(vp + (size_t)((t >> 2) + 64 * q) * NPIX);
}

__device__ __forceinline__ void stg_write(u16* __restrict__ kb, u16* __restrict__ vb,
                                          int t, const SR& R) {
    #pragma unroll
    for (int q = 0; q < 2; ++q) {
        const int idx = t + 256 * q;
        const int row = idx >> 4;
        const int ch  = (idx & 15) ^ (row & 15);
        *(uint4*)(kb + row * 128 + ch * 8) = R.k[q];
    }
    #pragma unroll
    for (int q = 0; q < 4; ++q) {
        const int c   = (t >> 2) + 64 * q;
        const int rc  = c >> 1;
        const int q8  = (c & 1) * 8 + (t & 3) * 2;
        const int x   = rc & 15;
        const int ch0 = q8 ^ x;
        const int ch1 = (q8 + 1) ^ x;
        *(uint2*)(vb + rc * 64 + ch0 * 4) = make_uint2(R.v[q].x, R.v[q].y);
        *(uint2*)(vb + rc * 64 + ch1 * 4) = make_uint2(R.v[q].z, R.v[q].w);
    }
}

__global__ __launch_bounds__(256, 2)
void attn_mfma3(const u16* __restrict__ qt,   // [BS][NPIX][C2]
                const u16* __restrict__ kt,   // [BS][NPIX][C2]
                const u16* __restrict__ vn,   // [BS][C][NPIX]
                u16* __restrict__ opart0,     // bf16 partial O, j-half 0 (ws)
                u16* __restrict__ opart1,     // bf16 partial O, j-half 1 (ws)
                float* __restrict__ sbuf) {   // [2][BS][NPIX] partial sums
    __shared__ u16 Kb[2][32 * 128];
    __shared__ u16 Vb[2][128 * 64];

    const int t  = threadIdx.x;
    const int w  = t >> 6;
    const int li = t & 31;
    const int hs = (t >> 5) & 1;

    const int b  = blockIdx.x & 7;                 // batch <-> XCD affinity
    const int it = (blockIdx.x >> 3) & 31;
    const int h  = blockIdx.x >> 8;                // j-half
    const int i0 = it * 128;
    const int iw = i0 + w * 32 + li;
    const int j0 = h * 2048;

    bf16x8 qf[8];
    {
        const u16* qp = qt + ((size_t)b * NPIX + iw) * C2 + hs * 8;
        #pragma unroll
        for (int ct = 0; ct < 8; ++ct) qf[ct] = *(const bf16x8*)(qp + ct * 16);
    }

    f32x16 oacc[8];
    #pragma unroll
    for (int ct = 0; ct < 8; ++ct)
        #pragma unroll
        for (int e = 0; e < 16; ++e) oacc[ct][e] = 0.f;

    const u16* ktb = kt + ((size_t)b * NPIX + j0) * C2;
    const u16* vnb = vn + (size_t)b * C * NPIX + j0;

    SR R;
    stg_load(ktb, vnb, 0, t, R);
    stg_write(&Kb[0][0], &Vb[0][0], t, R);
    stg_load(ktb, vnb, 1, t, R);
    __syncthreads();

    float ssl = 0.f;
    for (int itr = 0; itr < 64; ++itr) {
        const int cur = itr & 1;
        if (itr < 63) {
            stg_write(&Kb[cur ^ 1][0], &Vb[cur ^ 1][0], t, R);
            if (itr < 62) stg_load(ktb, vnb, itr + 2, t, R);
        }
        const u16* kb = &Kb[cur][0];
        const u16* vb = &Vb[cur][0];

        // ---- S' = K Q^T  [32j x 32i]
        f32x16 s;
        #pragma unroll
        for (int e = 0; e < 16; ++e) s[e] = 0.f;
        {
            const int xr = li & 15;
            __builtin_amdgcn_s_setprio(1);
            #pragma unroll
            for (int ct = 0; ct < 8; ++ct) {
                const int ch = (ct * 2 + hs) ^ xr;
                const bf16x8 kf = *(const bf16x8*)(kb + li * 128 + ch * 8);
                s = __builtin_amdgcn_mfma_f32_32x32x16_bf16(kf, qf[ct], s, 0, 0, 0);
            }
            __builtin_amdgcn_s_setprio(0);
        }

        // ---- P = exp(S'), partial sums, pack bf16 pairs (native cvt)
        u32 pk[8];
        #pragma unroll
        for (int n = 0; n < 8; ++n) {
            const float p0 = __expf(s[2 * n]);
            const float p1 = __expf(s[2 * n + 1]);
            ssl += p0 + p1;
            union { bf16_t e[2]; u32 u; } cv;
            cv.e[0] = (bf16_t)p0;
            cv.e[1] = (bf16_t)p1;
            pk[n] = cv.u;
        }

        // ---- P' -> PV B-fragments via half-swap shuffle
        bf16x8 pf[2];
        #pragma unroll
        for (int seg = 0; seg < 2; ++seg) {
            const u32 A0 = pk[4 * seg + 0], A1 = pk[4 * seg + 1];
            const u32 A2 = pk[4 * seg + 2], A3 = pk[4 * seg + 3];
            const u32 own0 = hs ? A2 : A0, own1 = hs ? A3 : A1;
            const u32 snd0 = hs ? A0 : A2, snd1 = hs ? A1 : A3;
            const u32 rcv0 = (u32)__shfl_xor((int)snd0, 32, 64);
            const u32 rcv1 = (u32)__shfl_xor((int)snd1, 32, 64);
            union { u32 u[4]; bf16x8 v; } bb;
            bb.u[0] = hs ? rcv0 : own0;
            bb.u[1] = hs ? rcv1 : own1;
            bb.u[2] = hs ? own0 : rcv0;
            bb.u[3] = hs ? own1 : rcv1;
            pf[seg] = bb.v;
        }

        // ---- O += V P'
        __builtin_amdgcn_s_setprio(1);
        #pragma unroll
        for (int ct = 0; ct < 8; ++ct) {
            const int c  = ct * 32 + li;
            const int rc = c >> 1;
            const int x  = rc & 15;
            const u16* vr = vb + rc * 64;
            const int cb = (c & 1) * 8 + hs * 2;
            #pragma unroll
            for (int seg = 0; seg < 2; ++seg) {
                const int q8  = cb + seg * 4;
                const int ch0 = q8 ^ x;
                const int ch1 = (q8 + 1) ^ x;
                union { uint2 g[2]; bf16x8 v8; } u;
                u.g[0] = *(const uint2*)(vr + ch0 * 4);
                u.g[1] = *(const uint2*)(vr + ch1 * 4);
                oacc[ct] = __builtin_amdgcn_mfma_f32_32x32x16_bf16(u.v8, pf[seg], oacc[ct], 0, 0, 0);
            }
        }
        __builtin_amdgcn_s_setprio(0);
        __syncthreads();
    }

    // ---- partial denominators
    ssl += __shfl_xor(ssl, 32, 64);
    if (hs == 0) sbuf[((size_t)h * BS + b) * NPIX + iw] = ssl;

    // ---- store unnormalized partial O (bf16, native cvt)
    u16* op = h ? opart1 : opart0;
    #pragma unroll
    for (int ct = 0; ct < 8; ++ct) {
        #pragma unroll
        for (int r = 0; r < 16; ++r) {
            const int c = ct * 32 + (r & 3) + 8 * (r >> 2) + 4 * hs;
            union { bf16_t e; u16 u; } cv;
            cv.e = (bf16_t)oacc[ct][r];
            op[((size_t)b * C + c) * NPIX + iw] = cv.u;
        }
    }
}

// ---- merge: out = (O1+O2)/(s1+s2); fuse = out*motion (bf16 partials) -------
__global__ __launch_bounds__(256)
void attn_merge(float* __restrict__ fuse, float* __restrict__ outp,
                const u16* __restrict__ pa, const u16* __restrict__ pb,
                const float* __restrict__ motion,
                const float* __restrict__ sbuf) {
    const size_t idx = ((size_t)blockIdx.x * 256 + threadIdx.x) * 8;
    const int n = (int)(idx & (NPIX - 1));
    const int b = (int)(idx >> 20);
    const uint4 A = *(const uint4*)(pa + idx);
    const uint4 B = *(const uint4*)(pb + idx);
    const u32 au[4] = {A.x, A.y, A.z, A.w};
    const u32 bu[4] = {B.x, B.y, B.z, B.w};
    float den[8];
    {
        const float* s0 = sbuf + (size_t)b * NPIX + n;
        const float* s1 = sbuf + (size_t)(BS + b) * NPIX + n;
        const float4 s0a = *(const float4*)s0;
        const float4 s0b = *(const float4*)(s0 + 4);
        const float4 s1a = *(const float4*)s1;
        const float4 s1b = *(const float4*)(s1 + 4);
        den[0] = s0a.x + s1a.x; den[1] = s0a.y + s1a.y;
        den[2] = s0a.z + s1a.z; den[3] = s0a.w + s1a.w;
        den[4] = s0b.x + s1b.x; den[5] = s0b.y + s1b.y;
        den[6] = s0b.z + s1b.z; den[7] = s0b.w + s1b.w;
    }
    float o[8];
    #pragma unroll
    for (int q = 0; q < 4; ++q) {
        o[2 * q]     = (bf2f((u16)(au[q] & 0xffffu)) + bf2f((u16)(bu[q] & 0xffffu))) / den[2 * q];
        o[2 * q + 1] = (bf2f((u16)(au[q] >> 16))     + bf2f((u16)(bu[q] >> 16)))     / den[2 * q + 1];
    }
    const float4 m0 = *(const float4*)(motion + idx);
    const float4 m1 = *(const float4*)(motion + idx + 4);
    *(float4*)(outp + idx)     = make_float4(o[0], o[1], o[2], o[3]);
    *(float4*)(outp + idx + 4) = make_float4(o[4], o[5], o[6], o[7]);
    *(float4*)(fuse + idx)     = make_float4(o[0] * m0.x, o[1] * m0.y, o[2] * m0.z, o[3] * m0.w);
    *(float4*)(fuse + idx + 4) = make_float4(o[4] * m1.x, o[5] * m1.y, o[6] * m1.z, o[7] * m1.w);
}

extern "C" void kernel_launch(void* const* d_in, const int* in_sizes, int n_in,
                              void* d_out, int out_size, void* d_ws, size_t ws_size,
                              hipStream_t stream) {
    const float* a1     = (const float*)d_in[0];  // appearance_1 -> k
    const float* a2     = (const float*)d_in[1];  // appearance_2 -> q
    const float* motion = (const float*)d_in[2];  // -> v, and fuse multiplier
    const float* Wq = (const float*)d_in[3];
    const float* bq = (const float*)d_in[4];
    const float* Wk = (const float*)d_in[5];
    const float* bk = (const float*)d_in[6];
    const float* Wv = (const float*)d_in[7];
    const float* bv = (const float*)d_in[8];

    float* outp = (float*)d_out;  // [fuse_out | out]
    float* slot0 = outp;                              // fuse_out
    float* slot1 = outp + (size_t)BS * C * NPIX;      // out

    // workspace: QT (8MB) | KT (8MB) | V (16MB) | sbuf (256KB) | W frags |
    //            bf16 partials pw0/pw1 (16.8MB each). Total ~67.4MB
    u16* qws = (u16*)d_ws;
    u16* kws = qws + (size_t)BS * C2 * NPIX;
    u16* vws = kws + (size_t)BS * C2 * NPIX;
    float* sbuf = (float*)(vws + (size_t)BS * C * NPIX);
    u16* wqh = (u16*)(sbuf + (size_t)2 * BS * NPIX);
    u16* wql = wqh + C2 * C2;
    u16* wkh = wql + C2 * C2;
    u16* wkl = wkh + C2 * C2;
    u16* wvh = wkl + C2 * C2;
    u16* wvl = wvh + C * C;
    u16* pw0 = wvl + C * C;
    u16* pw1 = pw0 + (size_t)BS * C * NPIX;

    const dim3 blk(256);
    prep_w<<<dim3(32, 3), blk, 0, stream>>>(Wq, Wk, Wv, wqh, wql, wkh, wkl, wvh, wvl);
    proj_all<<<dim3(NPIX / 64, BS, 4), blk, 0, stream>>>(
        wqh, wql, wkh, wkl, wvh, wvl, bq, bk, bv, a2, a1, motion, qws, kws, vws);

    attn_mfma3<<<dim3(512), blk, 0, stream>>>(qws, kws, vws, pw0, pw1, sbuf);

    attn_merge<<<dim3((BS * C * NPIX) / 2048), blk, 0, stream>>>(
        slot0, slot1, pw0, pw1, motion, sbuf);
}